// Round 8
// baseline (1037.077 us; speedup 1.0000x reference)
//
#include <hip/hip_runtime.h>
#include <cmath>

#define NEG -1e9f
#define LOG2E 1.44269504088896340736f
constexpr int B = 8, N = 512, M = 512, D = 512;
constexpr size_t NM = (size_t)N * M;   // 262144

// CH = 16: chunk = barrier interval = wave skew (16 diagonals per chunk).
// Forward: wave w active chunks [5w, 5w+35]; backward: [35-5w, 70-5w], K0=1134.
constexpr int NCHUNK = 72;      // even; compute chunks end at 70

// Native-hardware transcendentals (v_exp_f32 = 2^x, v_log_f32 = log2 x).
#define EXP2F(x) __builtin_amdgcn_exp2f(x)
#define LOG2F(x) __builtin_amdgcn_logf(x)

typedef float f32x2 __attribute__((ext_vector_type(2)));

// DPP full-wave shifts (register-file; replaces ds_bpermute).
__device__ __forceinline__ float dpp_shr1(float v) {
    return __int_as_float(__builtin_amdgcn_update_dpp(
        __float_as_int(v), __float_as_int(v), 0x138, 0xf, 0xf, false));
}
__device__ __forceinline__ float dpp_shl1(float v) {
    return __int_as_float(__builtin_amdgcn_update_dpp(
        __float_as_int(v), __float_as_int(v), 0x130, 0xf, 0xf, false));
}

// Compact diagonal layout: cell (r,c) 0-based -> diag_off(kd) + r - max(0,kd-511)
__device__ __forceinline__ int diag_off(int kd) {
    return (kd <= 511) ? ((kd * (kd + 1)) >> 1)
                       : ((int)NM - (((1023 - kd) * (1024 - kd)) >> 1));
}

// ---------------------------------------------------------------------------
// GEMM + activation: which=0 -> theta = softplus(zx . zy^T)
//                    which=1 -> A     = log_sigmoid(gx . gy^T)
// ---------------------------------------------------------------------------
__global__ __launch_bounds__(256)
void gemm_act_kernel(const float* __restrict__ zx, const float* __restrict__ zy,
                     const float* __restrict__ gx, const float* __restrict__ gy,
                     float* __restrict__ out_theta, float* __restrict__ out_A)
{
    const int bz = blockIdx.z;
    const int b = bz >> 1, which = bz & 1;
    const float* X = (which ? gx : zx) + (size_t)b * N * D;
    const float* Y = (which ? gy : zy) + (size_t)b * M * D;
    float* C = (which ? out_A : out_theta) + (size_t)b * NM;

    __shared__ float Xs[16][68];
    __shared__ float Ys[16][68];

    const int tx = threadIdx.x, ty = threadIdx.y;
    const int t = ty * 16 + tx;
    const int lrow = t >> 2;
    const int lk4 = (t & 3) * 4;
    const int row0 = blockIdx.y * 64, col0 = blockIdx.x * 64;

    float acc[4][4] = {};

    for (int k0 = 0; k0 < D; k0 += 16) {
        const float4 xv = *(const float4*)&X[(row0 + lrow) * D + k0 + lk4];
        const float4 yv = *(const float4*)&Y[(col0 + lrow) * D + k0 + lk4];
        Xs[lk4 + 0][lrow] = xv.x; Xs[lk4 + 1][lrow] = xv.y;
        Xs[lk4 + 2][lrow] = xv.z; Xs[lk4 + 3][lrow] = xv.w;
        Ys[lk4 + 0][lrow] = yv.x; Ys[lk4 + 1][lrow] = yv.y;
        Ys[lk4 + 2][lrow] = yv.z; Ys[lk4 + 3][lrow] = yv.w;
        __syncthreads();
#pragma unroll
        for (int kk = 0; kk < 16; kk++) {
            const float4 a = *(const float4*)&Xs[kk][ty * 4];
            const float4 bb = *(const float4*)&Ys[kk][tx * 4];
            acc[0][0] += a.x * bb.x; acc[0][1] += a.x * bb.y; acc[0][2] += a.x * bb.z; acc[0][3] += a.x * bb.w;
            acc[1][0] += a.y * bb.x; acc[1][1] += a.y * bb.y; acc[1][2] += a.y * bb.z; acc[1][3] += a.y * bb.w;
            acc[2][0] += a.z * bb.x; acc[2][1] += a.z * bb.y; acc[2][2] += a.z * bb.z; acc[2][3] += a.z * bb.w;
            acc[3][0] += a.w * bb.x; acc[3][1] += a.w * bb.y; acc[3][2] += a.w * bb.z; acc[3][3] += a.w * bb.w;
        }
        __syncthreads();
    }

#pragma unroll
    for (int r = 0; r < 4; r++) {
        float4 o;
        float* op = &o.x;
#pragma unroll
        for (int c = 0; c < 4; c++) {
            const float x = acc[r][c];
            const float l = log1pf(expf(-fabsf(x)));
            op[c] = which ? (fminf(x, 0.0f) - l)     // log_sigmoid
                          : (fmaxf(x, 0.0f) + l);   // softplus
        }
        *(float4*)&C[(size_t)(row0 + ty * 4 + r) * M + col0 + tx * 4] = o;
    }
}

// ---------------------------------------------------------------------------
// Row-major theta,A -> compact-diag interleaved float2 {theta, A}, scaled by
// log2(e) so the DP kernel can use native exp2/log2 (p-ratios are invariant).
// ---------------------------------------------------------------------------
__global__ __launch_bounds__(256)
void reorder_in_kernel(const float* __restrict__ theta, const float* __restrict__ A,
                       float2* __restrict__ TAD)
{
    __shared__ float T[64][67];
    __shared__ float Ag[64][67];
    const int b = blockIdx.z;
    const float* ts = theta + (size_t)b * NM;
    const float* as = A + (size_t)b * NM;
    float2* dst = TAD + (size_t)b * NM;
    const int r0 = blockIdx.y * 64, c0 = blockIdx.x * 64;
    const int t = threadIdx.x, lane = t & 63, wv = t >> 6;

#pragma unroll
    for (int e = 0; e < 16; e++) {
        const int r = wv * 16 + e;
        T[r][lane]  = ts[(size_t)(r0 + r) * M + c0 + lane];
        Ag[r][lane] = as[(size_t)(r0 + r) * M + c0 + lane];
    }
    __syncthreads();
    for (int dd = wv; dd < 127; dd += 4) {
        const int kd = r0 + c0 + dd;
        const int rlo = max(0, dd - 63);
        const int L = min(63, dd) - rlo + 1;
        if (lane < L) {
            const int rloc = rlo + lane;
            const int gr = r0 + rloc;
            dst[diag_off(kd) + gr - max(0, kd - 511)] =
                make_float2(T[rloc][dd - rloc] * LOG2E, Ag[rloc][dd - rloc] * LOG2E);
        }
    }
}

// ---------------------------------------------------------------------------
// Compact-diag E -> row-major aln.
// ---------------------------------------------------------------------------
__global__ __launch_bounds__(256)
void reorder_out_kernel(const float* __restrict__ ED, float* __restrict__ aln)
{
    __shared__ float T[64][67];
    const int b = blockIdx.z;
    const float* src = ED + (size_t)b * NM;
    float* dst = aln + (size_t)b * NM;
    const int r0 = blockIdx.y * 64, c0 = blockIdx.x * 64;
    const int t = threadIdx.x, lane = t & 63, wv = t >> 6;

    for (int dd = wv; dd < 127; dd += 4) {
        const int kd = r0 + c0 + dd;
        const int rlo = max(0, dd - 63);
        const int L = min(63, dd) - rlo + 1;
        if (lane < L) {
            const int rloc = rlo + lane;
            const int gr = r0 + rloc;
            T[rloc][dd - rloc] = src[diag_off(kd) + gr - max(0, kd - 511)];
        }
    }
    __syncthreads();
#pragma unroll
    for (int e = 0; e < 16; e++) {
        const int r = wv * 16 + e;
        dst[(size_t)(r0 + r) * M + c0 + lane] = T[r][lane];
    }
}

// ---------------------------------------------------------------------------
// Fences. Chunk top: if the previous chunk issued exactly 16 stores (interior
// path), vmcnt(16) drains ONLY the 16 older loads and leaves stores in flight
// (vmcnt retires in issue order). Otherwise conservative vmcnt(0).
// CHUNK_BARRIER: LDS drain + raw s_barrier; loads/stores stay in flight.
// ---------------------------------------------------------------------------
#define VMCNT_TOP_PF                                        \
    if (pf) { asm volatile("s_waitcnt vmcnt(16)"); }        \
    else    { asm volatile("s_waitcnt vmcnt(0)");  }        \
    __builtin_amdgcn_sched_barrier(0);

#define CHUNK_BARRIER                          \
    __builtin_amdgcn_sched_barrier(0);         \
    asm volatile("s_waitcnt lgkmcnt(0)");      \
    __builtin_amdgcn_s_barrier();              \
    __builtin_amdgcn_sched_barrier(0);

#define DECL16(P)  f32x2 P##0, P##1, P##2, P##3, P##4, P##5, P##6, P##7, \
                         P##8, P##9, P##10, P##11, P##12, P##13, P##14, P##15;
#define DECL16F(P) float P##0, P##1, P##2, P##3, P##4, P##5, P##6, P##7, \
                         P##8, P##9, P##10, P##11, P##12, P##13, P##14, P##15;

// ---------------------------------------------------------------------------
// Forward soft-NW. Rolled chunk loop (I$-resident body), streaming incremental
// diag addressing (running byte offset, SGPR-base loads/stores), asm-issued
// register prefetch, batched stores, base-2 math, store-decoupled waitcnt.
// ---------------------------------------------------------------------------
#define FLOAD1(dst) {                                          \
    asm volatile("global_load_dwordx2 %0, %1, %2"              \
                 : "=v"(dst) : "v"(off8l), "s"(tab));          \
    const int d_ = (kdl <= 510) ? max(kdl + 1, 0)              \
                                : max(1022 - kdl, 0);          \
    off8l += d_ * 8; kdl++;                                    \
}
#define F_ISSUE(P) {                                           \
    FLOAD1(P##0)  FLOAD1(P##1)  FLOAD1(P##2)  FLOAD1(P##3)     \
    FLOAD1(P##4)  FLOAD1(P##5)  FLOAD1(P##6)  FLOAD1(P##7)     \
    FLOAD1(P##8)  FLOAD1(P##9)  FLOAD1(P##10) FLOAD1(P##11)    \
    FLOAD1(P##12) FLOAD1(P##13) FLOAD1(P##14) FLOAD1(P##15)    \
}

#define F_CORE(kd_, TA, sh1v, dgv, O) {                        \
    const float th = (TA).x, a = (TA).y;                       \
    const float x0 = a + sh1v;                                 \
    const float x2 = a + vprev;                                \
    const float mx = fmaxf(fmaxf(x0, dgv), x2);                \
    const float e0 = EXP2F(x0 - mx);                           \
    const float e1 = EXP2F(dgv - mx);                          \
    const float e2 = EXP2F(x2 - mx);                           \
    const float sum = e0 + e1 + e2;                            \
    const float inv = __builtin_amdgcn_rcpf(sum);              \
    (O).x = e0 * inv; (O).y = e2 * inv;                        \
    vprev = th + mx + LOG2F(sum);                              \
    if (lane == 63) ring[w][(kd_) & 63] = vprev;               \
}

// interior: every lane valid, jj>=1 guaranteed -> no selects, no exec juggling
#define F_STEP_I(s, TA, O, RG) {                               \
    const int kd = kb + (s);                                   \
    float sh1 = dpp_shr1(vprev);                               \
    if (lane == 0) sh1 = RG;                                   \
    const float dgv = sh1_d;                                   \
    sh1_d = sh1;                                               \
    F_CORE(kd, TA, sh1, dgv, O)                                \
}

#define F_STEP_G(s, TA, O, RG) {                               \
    const int kd = kb + (s);                                   \
    const int jj = kd - tid;                                   \
    float sh1 = dpp_shr1(vprev);                               \
    if (lane == 0) sh1 = RG;                                   \
    const float dgv = (jj == 0) ? ((tid == 0) ? 0.0f : NEG) : sh1_d; \
    sh1_d = sh1;                                               \
    if (jj >= 0 && jj < M) { F_CORE(kd, TA, sh1, dgv, O) }     \
}

#define F_STEPS(SFX, CUR)                                                    \
    F_STEP_##SFX(0,  CUR##0,  o0,  r0)  F_STEP_##SFX(1,  CUR##1,  o1,  r1)   \
    F_STEP_##SFX(2,  CUR##2,  o2,  r2)  F_STEP_##SFX(3,  CUR##3,  o3,  r3)   \
    F_STEP_##SFX(4,  CUR##4,  o4,  r4)  F_STEP_##SFX(5,  CUR##5,  o5,  r5)   \
    F_STEP_##SFX(6,  CUR##6,  o6,  r6)  F_STEP_##SFX(7,  CUR##7,  o7,  r7)   \
    F_STEP_##SFX(8,  CUR##8,  o8,  r8)  F_STEP_##SFX(9,  CUR##9,  o9,  r9)   \
    F_STEP_##SFX(10, CUR##10, o10, r10) F_STEP_##SFX(11, CUR##11, o11, r11)  \
    F_STEP_##SFX(12, CUR##12, o12, r12) F_STEP_##SFX(13, CUR##13, o13, r13)  \
    F_STEP_##SFX(14, CUR##14, o14, r14) F_STEP_##SFX(15, CUR##15, o15, r15)

#define F_ADV_S { const int d_ = (kds <= 510) ? (kds + 1) : (1022 - kds);    \
                  off8s += d_ * 8; kds++; }
#define FST_I(O) {                                                           \
    asm volatile("global_store_dwordx2 %0, %1, %2"                           \
                 :: "v"(off8s), "v"(O), "s"(pb) : "memory");                 \
    F_ADV_S }
#define FST_G(s, O) {                                                        \
    const int jj = kb + (s) - tid;                                           \
    if (jj >= 0 && jj < M) {                                                 \
        asm volatile("global_store_dwordx2 %0, %1, %2"                       \
                     :: "v"(off8s), "v"(O), "s"(pb) : "memory"); }           \
    F_ADV_S }
#define F_STORES_I {                                                         \
    FST_I(o0)  FST_I(o1)  FST_I(o2)  FST_I(o3)                               \
    FST_I(o4)  FST_I(o5)  FST_I(o6)  FST_I(o7)                               \
    FST_I(o8)  FST_I(o9)  FST_I(o10) FST_I(o11)                              \
    FST_I(o12) FST_I(o13) FST_I(o14) FST_I(o15) }
#define F_STORES_G {                                                         \
    FST_G(0,o0)   FST_G(1,o1)   FST_G(2,o2)   FST_G(3,o3)                    \
    FST_G(4,o4)   FST_G(5,o5)   FST_G(6,o6)   FST_G(7,o7)                    \
    FST_G(8,o8)   FST_G(9,o9)   FST_G(10,o10) FST_G(11,o11)                  \
    FST_G(12,o12) FST_G(13,o13) FST_G(14,o14) FST_G(15,o15) }

#define F_CHUNK(c_, CUR, NXT) {                                \
    const int c = (c_);                                        \
    VMCNT_TOP_PF             /* CUR loads now valid */         \
    F_ISSUE(NXT)             /* next-chunk loads in flight */  \
    const int kb = 16 * c - w16;                               \
    const int kr = kb - 64 * w;                                \
    const bool act = (c >= ca && c <= cb);                     \
    const bool interior = act && (kr >= 64) && (kr <= 496);    \
    if (act) {                                                 \
        float r0 = NEG, r1 = NEG, r2 = NEG, r3 = NEG,          \
              r4 = NEG, r5 = NEG, r6 = NEG, r7 = NEG,          \
              r8 = NEG, r9 = NEG, r10 = NEG, r11 = NEG,        \
              r12 = NEG, r13 = NEG, r14 = NEG, r15 = NEG;      \
        if (w > 0) {                                           \
            r0  = ring[w - 1][(kb - 1) & 63];                  \
            r1  = ring[w - 1][(kb + 0) & 63];                  \
            r2  = ring[w - 1][(kb + 1) & 63];                  \
            r3  = ring[w - 1][(kb + 2) & 63];                  \
            r4  = ring[w - 1][(kb + 3) & 63];                  \
            r5  = ring[w - 1][(kb + 4) & 63];                  \
            r6  = ring[w - 1][(kb + 5) & 63];                  \
            r7  = ring[w - 1][(kb + 6) & 63];                  \
            r8  = ring[w - 1][(kb + 7) & 63];                  \
            r9  = ring[w - 1][(kb + 8) & 63];                  \
            r10 = ring[w - 1][(kb + 9) & 63];                  \
            r11 = ring[w - 1][(kb + 10) & 63];                 \
            r12 = ring[w - 1][(kb + 11) & 63];                 \
            r13 = ring[w - 1][(kb + 12) & 63];                 \
            r14 = ring[w - 1][(kb + 13) & 63];                 \
            r15 = ring[w - 1][(kb + 14) & 63];                 \
        }                                                      \
        DECL16(o)                                              \
        if (interior) {                                        \
            F_STEPS(I, CUR)                                    \
            F_STORES_I                                         \
        } else {                                               \
            F_STEPS(G, CUR)                                    \
            F_STORES_G                                         \
        }                                                      \
    }                                                          \
    pf = interior;                                             \
    CHUNK_BARRIER                                              \
}

__global__ __launch_bounds__(512, 1)
void nw_forward_kernel(const float2* __restrict__ TAD, float2* __restrict__ pD)
{
    __shared__ float ring[8][64];
    const int b = blockIdx.x;
    const int tid = threadIdx.x;
    const int w = __builtin_amdgcn_readfirstlane(tid >> 6);
    const int lane = tid & 63;
    const int w16 = 16 * w;
    const float2* tab = TAD + (size_t)b * NM;
    float2* pb = pD + (size_t)b * NM;

    for (int x = tid; x < 8 * 64; x += 512) ((float*)ring)[x] = NEG;
    __syncthreads();

    const int ca = 5 * w, cb = 5 * w + 35;

    // streaming address state (byte offsets; SGPR-base loads/stores)
    int kdl = -w16;
    int off8l = tid * 8;                             // extended fi(kd<=0) = tid
    int kds = 64 * w;
    int off8s = (((kds * (kds + 1)) >> 1) + tid) * 8; // fi(64w), 64w<=448<512

    DECL16(fa) DECL16(fb)
    F_ISSUE(fa)

    float vprev = NEG, sh1_d = NEG;
    bool pf = false;

#pragma unroll 1
    for (int c2 = 0; c2 < NCHUNK; c2 += 2) {
        F_CHUNK(c2 + 0, fa, fb)
        F_CHUNK(c2 + 1, fb, fa)
    }
}

// ---------------------------------------------------------------------------
// Backward adjoint, q-product form, mirrored skew (wave 7 leads), K0 = 1134.
// Same rolled-loop + streaming-addressing + batched-store + decoupled-vmcnt.
// ---------------------------------------------------------------------------
#define BLOAD1(dst) {                                          \
    asm volatile("global_load_dwordx2 %0, %1, %2"              \
                 : "=v"(dst) : "v"(off8l), "s"(pbp));          \
    const int d_ = (kdl <= 511) ? (-max(kdl, 0))               \
                                : min(kdl - 1023, 0);          \
    off8l += d_ * 8; kdl--;                                    \
}
#define B_ISSUE(P) {                                           \
    BLOAD1(P##0)  BLOAD1(P##1)  BLOAD1(P##2)  BLOAD1(P##3)     \
    BLOAD1(P##4)  BLOAD1(P##5)  BLOAD1(P##6)  BLOAD1(P##7)     \
    BLOAD1(P##8)  BLOAD1(P##9)  BLOAD1(P##10) BLOAD1(P##11)    \
    BLOAD1(P##12) BLOAD1(P##13) BLOAD1(P##14) BLOAD1(P##15)    \
}

#define B_CORE(kd_, PP, suv, sdv, EV, TERMFIX) {               \
    float e = suv + sdv + ql1;                                 \
    TERMFIX                                                    \
    const float pu = (PP).x, pl = (PP).y;                      \
    const float pd = 1.0f - pu - pl;                           \
    const float qu = pu * e, qd = pd * e, ql = pl * e;         \
    EV = e;                                                    \
    qd2 = qd1; qd1 = qd; qu1 = qu; ql1 = ql;                   \
    if (lane == 0) {                                           \
        ring_u[w][(kd_) & 63] = qu;                            \
        ring_d[w][(kd_) & 63] = qd;                            \
    }                                                          \
}

#define B_STEP_I(s, PP, EV, RU, RD) {                          \
    const int kd = kb - (s);                                   \
    float su = dpp_shl1(qu1);                                  \
    float sd = dpp_shl1(qd2);                                  \
    if (lane == 63) { su = RU; sd = RD; }                      \
    B_CORE(kd, PP, su, sd, EV, )                               \
}

#define B_STEP_G(s, PP, EV, RU, RD) {                          \
    const int kd = kb - (s);                                   \
    const int jj = kd - tid;                                   \
    float su = dpp_shl1(qu1);                                  \
    float sd = dpp_shl1(qd2);                                  \
    if (lane == 63) { su = RU; sd = RD; }                      \
    if (jj >= 0 && jj < M) {                                   \
        B_CORE(kd, PP, su, sd, EV,                             \
               if (tid == N - 1 && jj == M - 1) e = 1.0f;)     \
    }                                                          \
}

#define B_STEPS(SFX, CUR)                                                          \
    B_STEP_##SFX(0,  CUR##0,  ev0,  ru0,  rd0)  B_STEP_##SFX(1,  CUR##1,  ev1,  ru1,  rd1)  \
    B_STEP_##SFX(2,  CUR##2,  ev2,  ru2,  rd2)  B_STEP_##SFX(3,  CUR##3,  ev3,  ru3,  rd3)  \
    B_STEP_##SFX(4,  CUR##4,  ev4,  ru4,  rd4)  B_STEP_##SFX(5,  CUR##5,  ev5,  ru5,  rd5)  \
    B_STEP_##SFX(6,  CUR##6,  ev6,  ru6,  rd6)  B_STEP_##SFX(7,  CUR##7,  ev7,  ru7,  rd7)  \
    B_STEP_##SFX(8,  CUR##8,  ev8,  ru8,  rd8)  B_STEP_##SFX(9,  CUR##9,  ev9,  ru9,  rd9)  \
    B_STEP_##SFX(10, CUR##10, ev10, ru10, rd10) B_STEP_##SFX(11, CUR##11, ev11, ru11, rd11) \
    B_STEP_##SFX(12, CUR##12, ev12, ru12, rd12) B_STEP_##SFX(13, CUR##13, ev13, ru13, rd13) \
    B_STEP_##SFX(14, CUR##14, ev14, ru14, rd14) B_STEP_##SFX(15, CUR##15, ev15, ru15, rd15)

#define B_ADV_S { const int d_ = (kds <= 511) ? (-max(kds, 0))               \
                                              : min(kds - 1023, 0);          \
                  off4s += d_ * 4; kds--; }
#define BST_I(EV) {                                                          \
    asm volatile("global_store_dword %0, %1, %2"                             \
                 :: "v"(off4s), "v"(EV), "s"(ebp) : "memory");               \
    B_ADV_S }
#define BST_G(s, EV) {                                                       \
    const int jj = kb - (s) - tid;                                           \
    if (jj >= 0 && jj < M) {                                                 \
        asm volatile("global_store_dword %0, %1, %2"                         \
                     :: "v"(off4s), "v"(EV), "s"(ebp) : "memory"); }         \
    B_ADV_S }
#define B_STORES_I {                                                         \
    BST_I(ev0)  BST_I(ev1)  BST_I(ev2)  BST_I(ev3)                           \
    BST_I(ev4)  BST_I(ev5)  BST_I(ev6)  BST_I(ev7)                           \
    BST_I(ev8)  BST_I(ev9)  BST_I(ev10) BST_I(ev11)                          \
    BST_I(ev12) BST_I(ev13) BST_I(ev14) BST_I(ev15) }
#define B_STORES_G {                                                         \
    BST_G(0,ev0)   BST_G(1,ev1)   BST_G(2,ev2)   BST_G(3,ev3)                \
    BST_G(4,ev4)   BST_G(5,ev5)   BST_G(6,ev6)   BST_G(7,ev7)                \
    BST_G(8,ev8)   BST_G(9,ev9)   BST_G(10,ev10) BST_G(11,ev11)              \
    BST_G(12,ev12) BST_G(13,ev13) BST_G(14,ev14) BST_G(15,ev15) }

#define B_CHUNK(c_, CUR, NXT) {                                \
    const int c = (c_);                                        \
    VMCNT_TOP_PF                                               \
    B_ISSUE(NXT)                                               \
    const int kb = 1134 - 16 * c - w16;                        \
    const int krb = kb - 64 * w;                               \
    const bool act = (c >= ca && c <= cb);                     \
    const bool interior = act && (krb >= 78) && (krb <= 511);  \
    if (act) {                                                 \
        float ru0 = 0.f, ru1 = 0.f, ru2 = 0.f, ru3 = 0.f,      \
              ru4 = 0.f, ru5 = 0.f, ru6 = 0.f, ru7 = 0.f,      \
              ru8 = 0.f, ru9 = 0.f, ru10 = 0.f, ru11 = 0.f,    \
              ru12 = 0.f, ru13 = 0.f, ru14 = 0.f, ru15 = 0.f;  \
        float rd0 = 0.f, rd1 = 0.f, rd2 = 0.f, rd3 = 0.f,      \
              rd4 = 0.f, rd5 = 0.f, rd6 = 0.f, rd7 = 0.f,      \
              rd8 = 0.f, rd9 = 0.f, rd10 = 0.f, rd11 = 0.f,    \
              rd12 = 0.f, rd13 = 0.f, rd14 = 0.f, rd15 = 0.f;  \
        if (w < 7) {                                           \
            ru0  = ring_u[w + 1][(kb + 1)  & 63]; rd0  = ring_d[w + 1][(kb + 2)  & 63]; \
            ru1  = ring_u[w + 1][(kb + 0)  & 63]; rd1  = ring_d[w + 1][(kb + 1)  & 63]; \
            ru2  = ring_u[w + 1][(kb - 1)  & 63]; rd2  = ring_d[w + 1][(kb + 0)  & 63]; \
            ru3  = ring_u[w + 1][(kb - 2)  & 63]; rd3  = ring_d[w + 1][(kb - 1)  & 63]; \
            ru4  = ring_u[w + 1][(kb - 3)  & 63]; rd4  = ring_d[w + 1][(kb - 2)  & 63]; \
            ru5  = ring_u[w + 1][(kb - 4)  & 63]; rd5  = ring_d[w + 1][(kb - 3)  & 63]; \
            ru6  = ring_u[w + 1][(kb - 5)  & 63]; rd6  = ring_d[w + 1][(kb - 4)  & 63]; \
            ru7  = ring_u[w + 1][(kb - 6)  & 63]; rd7  = ring_d[w + 1][(kb - 5)  & 63]; \
            ru8  = ring_u[w + 1][(kb - 7)  & 63]; rd8  = ring_d[w + 1][(kb - 6)  & 63]; \
            ru9  = ring_u[w + 1][(kb - 8)  & 63]; rd9  = ring_d[w + 1][(kb - 7)  & 63]; \
            ru10 = ring_u[w + 1][(kb - 9)  & 63]; rd10 = ring_d[w + 1][(kb - 8)  & 63]; \
            ru11 = ring_u[w + 1][(kb - 10) & 63]; rd11 = ring_d[w + 1][(kb - 9)  & 63]; \
            ru12 = ring_u[w + 1][(kb - 11) & 63]; rd12 = ring_d[w + 1][(kb - 10) & 63]; \
            ru13 = ring_u[w + 1][(kb - 12) & 63]; rd13 = ring_d[w + 1][(kb - 11) & 63]; \
            ru14 = ring_u[w + 1][(kb - 13) & 63]; rd14 = ring_d[w + 1][(kb - 12) & 63]; \
            ru15 = ring_u[w + 1][(kb - 14) & 63]; rd15 = ring_d[w + 1][(kb - 13) & 63]; \
        }                                                      \
        DECL16F(ev)                                            \
        if (interior) {                                        \
            B_STEPS(I, CUR)                                    \
            B_STORES_I                                         \
        } else {                                               \
            B_STEPS(G, CUR)                                    \
            B_STORES_G                                         \
        }                                                      \
    }                                                          \
    pf = interior;                                             \
    CHUNK_BARRIER                                              \
}

__global__ __launch_bounds__(512, 1)
void nw_backward_kernel(const float2* __restrict__ pD, float* __restrict__ ED)
{
    __shared__ float ring_u[8][64];
    __shared__ float ring_d[8][64];
    const int b = blockIdx.x;
    const int tid = threadIdx.x;
    const int w = __builtin_amdgcn_readfirstlane(tid >> 6);
    const int lane = tid & 63;
    const int w16 = 16 * w;
    const float2* pbp = pD + (size_t)b * NM;
    float* ebp = ED + (size_t)b * NM;

    for (int x = tid; x < 8 * 64; x += 512) {
        ((float*)ring_u)[x] = 0.0f;
        ((float*)ring_d)[x] = 0.0f;
    }
    __syncthreads();

    const int ca = 35 - 5 * w, cb = 70 - 5 * w;

    // streaming address state (descending)
    int kdl = 1134 - w16;
    int off8l = ((int)NM - 512 + tid) * 8;           // fi(1022)
    int kds = 574 + 64 * w;                          // first active store kd
    const int am_ = 1023 - kds, bm_ = 1024 - kds;
    int off4s = ((int)NM - ((am_ * bm_) >> 1) + tid - (kds - 511)) * 4;

    DECL16(ba) DECL16(bb)
    B_ISSUE(ba)

    float qu1 = 0.0f, qd1 = 0.0f, qd2 = 0.0f, ql1 = 0.0f;
    bool pf = false;

#pragma unroll 1
    for (int c2 = 0; c2 < NCHUNK; c2 += 2) {
        B_CHUNK(c2 + 0, ba, bb)
        B_CHUNK(c2 + 1, bb, ba)
    }
}

// ---------------------------------------------------------------------------
// ABLATION PROBE 1: memory path only (loads + stores + vmcnt + barrier), no
// compute/ring. 3 reps x 36 chunks = 108 chunks (1.5x real wall-chunk count,
// sized to surface in top-5). 1 block; reads dead pD data, writes scratch.
// Per-chunk component cost = dur / 108; real = dur_real / 72.
// ---------------------------------------------------------------------------
#define PST1(P) {                                                            \
    asm volatile("global_store_dwordx2 %0, %1, %2"                           \
                 :: "v"(soff), "v"(P), "s"(scr) : "memory");                 \
    soff += 512 * 8; }
#define PSTORE16(P) {                                                        \
    PST1(P##0)  PST1(P##1)  PST1(P##2)  PST1(P##3)                           \
    PST1(P##4)  PST1(P##5)  PST1(P##6)  PST1(P##7)                           \
    PST1(P##8)  PST1(P##9)  PST1(P##10) PST1(P##11)                          \
    PST1(P##12) PST1(P##13) PST1(P##14) PST1(P##15) }

__global__ __launch_bounds__(512, 1)
void probe_mem(const float2* __restrict__ pDin, float2* __restrict__ scr)
{
    const int tid = threadIdx.x;
    const int w = __builtin_amdgcn_readfirstlane(tid >> 6);
    const int w16 = 16 * w;
    const f32x2* pbp = (const f32x2*)pDin;

#pragma unroll 1
    for (int rep = 0; rep < 3; rep++) {
        int kdl = 1134 - w16;
        int off8l = ((int)NM - 512 + tid) * 8;
        DECL16(na) DECL16(nb)
        B_ISSUE(na)
#pragma unroll 1
        for (int c2 = 0; c2 < 36; c2 += 2) {
            {
                asm volatile("s_waitcnt vmcnt(0)");
                __builtin_amdgcn_sched_barrier(0);
                B_ISSUE(nb)
                int soff = (((c2 & 7) * 16 * 512) + tid) * 8;
                PSTORE16(na)
                CHUNK_BARRIER
            }
            {
                asm volatile("s_waitcnt vmcnt(0)");
                __builtin_amdgcn_sched_barrier(0);
                B_ISSUE(na)
                int soff = ((((c2 + 1) & 7) * 16 * 512) + tid) * 8;
                PSTORE16(nb)
                CHUNK_BARRIER
            }
        }
        asm volatile("s_waitcnt vmcnt(0)");
    }
}

// ---------------------------------------------------------------------------
// ABLATION PROBE 2: compute path only (DPP chain + ring LDS + barrier), no
// global memory. 4 reps x 36 chunks = 144 chunks (2x real). All waves active
// every chunk (mid-pipeline regime). Per-chunk cost = dur / 144.
// ---------------------------------------------------------------------------
__global__ __launch_bounds__(512, 1)
void probe_cmp(float seed)
{
    __shared__ float ring_u[8][64];
    __shared__ float ring_d[8][64];
    const int tid = threadIdx.x;
    const int w = __builtin_amdgcn_readfirstlane(tid >> 6);
    const int lane = tid & 63;
    for (int x = tid; x < 8 * 64; x += 512) {
        ((float*)ring_u)[x] = seed;
        ((float*)ring_d)[x] = seed;
    }
    __syncthreads();

    float qu1 = seed, qd1 = 0.f, qd2 = 0.f, ql1 = seed;

#pragma unroll 1
    for (int c = 0; c < 144; ++c) {
        const int kb = 1134 - 16 * (c % 36) - 16 * w;
#pragma unroll
        for (int s = 0; s < 16; ++s) {
            const int kd = kb - s;
            float ru = 0.f, rd = 0.f;
            if (w < 7) {
                ru = ring_u[w + 1][(kd + 1) & 63];
                rd = ring_d[w + 1][(kd + 2) & 63];
            }
            float su = dpp_shl1(qu1);
            float sd = dpp_shl1(qd2);
            if (lane == 63) { su = ru; sd = rd; }
            const float e = su + sd + ql1;
            const float qu = 0.3f * e, qd = 0.4f * e, ql = 0.3f * e;
            qd2 = qd1; qd1 = qd; qu1 = qu; ql1 = ql;
            if (lane == 0) { ring_u[w][kd & 63] = qu; ring_d[w][kd & 63] = qd; }
        }
        CHUNK_BARRIER
    }
    asm volatile("" :: "v"(qu1), "v"(ql1), "v"(qd2));
}

// ---------------------------------------------------------------------------
extern "C" void kernel_launch(void* const* d_in, const int* in_sizes, int n_in,
                              void* d_out, int out_size, void* d_ws, size_t ws_size,
                              hipStream_t stream) {
    const float* zx = (const float*)d_in[0];
    const float* zy = (const float*)d_in[1];
    const float* gx = (const float*)d_in[2];
    const float* gy = (const float*)d_in[3];

    float* aln   = (float*)d_out;               // output 0: [B,N,M]
    float* theta = aln + B * NM;                // output 1
    float* Amat  = theta + B * NM;              // output 2

    float2* TAD = (float2*)d_ws;                // {theta,A}*log2e diag-interleaved
    float2* pD  = TAD + B * NM;                 // {p_up,p_lf} diag-interleaved
    float*  ED  = (float*)d_ws;                 // overlays TAD (dead after forward)

    gemm_act_kernel<<<dim3(8, 8, B * 2), dim3(16, 16), 0, stream>>>(zx, zy, gx, gy, theta, Amat);
    reorder_in_kernel<<<dim3(8, 8, B), 256, 0, stream>>>(theta, Amat, TAD);
    nw_forward_kernel<<<B, 512, 0, stream>>>(TAD, pD);
    nw_backward_kernel<<<B, 512, 0, stream>>>(pD, ED);
    // ablation probes: pD is dead after backward; probes read pD batch 0 and
    // write scratch inside the dead pD region (batches 4-7).
    probe_mem<<<1, 512, 0, stream>>>(pD, pD + 4 * NM);
    probe_cmp<<<1, 512, 0, stream>>>(0.5f);
    reorder_out_kernel<<<dim3(8, 8, B), 256, 0, stream>>>(ED, aln);
}

// Round 9
// 502.779 us; speedup vs baseline: 2.0627x; 2.0627x over previous
//
#include <hip/hip_runtime.h>
#include <cmath>

#define NEG -1e9f
#define LOG2E 1.44269504088896340736f
constexpr int B = 8, N = 512, M = 512, D = 512;
constexpr size_t NM = (size_t)N * M;   // 262144

// CH = 16: chunk = barrier interval = wave skew (16 diagonals per chunk).
// Forward: wave w active chunks [5w, 5w+35]; backward: [35-5w, 70-5w], K0=1134.
constexpr int NCHUNK = 72;      // even; compute chunks end at 70

// Native-hardware transcendentals (v_exp_f32 = 2^x, v_log_f32 = log2 x).
#define EXP2F(x) __builtin_amdgcn_exp2f(x)
#define LOG2F(x) __builtin_amdgcn_logf(x)

typedef float f32x2 __attribute__((ext_vector_type(2)));

// Prefetch load as inline asm (def can't be rematerialized/sunk).
#define GLOAD(dst, ptr) \
    asm volatile("global_load_dwordx2 %0, %1, off" : "=v"(dst) : "v"(ptr))

// DPP full-wave shifts (register-file; replaces ds_bpermute).
__device__ __forceinline__ float dpp_shr1(float v) {
    return __int_as_float(__builtin_amdgcn_update_dpp(
        __float_as_int(v), __float_as_int(v), 0x138, 0xf, 0xf, false));
}
__device__ __forceinline__ float dpp_shl1(float v) {
    return __int_as_float(__builtin_amdgcn_update_dpp(
        __float_as_int(v), __float_as_int(v), 0x130, 0xf, 0xf, false));
}

// Compact diagonal layout: cell (r,c) 0-based -> diag_off(kd) + r - max(0,kd-511)
__device__ __forceinline__ int diag_off(int kd) {
    return (kd <= 511) ? ((kd * (kd + 1)) >> 1)
                       : ((int)NM - (((1023 - kd) * (1024 - kd)) >> 1));
}

// ---------------------------------------------------------------------------
// GEMM + activation: which=0 -> theta = softplus(zx . zy^T)
//                    which=1 -> A     = log_sigmoid(gx . gy^T)
// ---------------------------------------------------------------------------
__global__ __launch_bounds__(256)
void gemm_act_kernel(const float* __restrict__ zx, const float* __restrict__ zy,
                     const float* __restrict__ gx, const float* __restrict__ gy,
                     float* __restrict__ out_theta, float* __restrict__ out_A)
{
    const int bz = blockIdx.z;
    const int b = bz >> 1, which = bz & 1;
    const float* X = (which ? gx : zx) + (size_t)b * N * D;
    const float* Y = (which ? gy : zy) + (size_t)b * M * D;
    float* C = (which ? out_A : out_theta) + (size_t)b * NM;

    __shared__ float Xs[16][68];
    __shared__ float Ys[16][68];

    const int tx = threadIdx.x, ty = threadIdx.y;
    const int t = ty * 16 + tx;
    const int lrow = t >> 2;
    const int lk4 = (t & 3) * 4;
    const int row0 = blockIdx.y * 64, col0 = blockIdx.x * 64;

    float acc[4][4] = {};

    for (int k0 = 0; k0 < D; k0 += 16) {
        const float4 xv = *(const float4*)&X[(row0 + lrow) * D + k0 + lk4];
        const float4 yv = *(const float4*)&Y[(col0 + lrow) * D + k0 + lk4];
        Xs[lk4 + 0][lrow] = xv.x; Xs[lk4 + 1][lrow] = xv.y;
        Xs[lk4 + 2][lrow] = xv.z; Xs[lk4 + 3][lrow] = xv.w;
        Ys[lk4 + 0][lrow] = yv.x; Ys[lk4 + 1][lrow] = yv.y;
        Ys[lk4 + 2][lrow] = yv.z; Ys[lk4 + 3][lrow] = yv.w;
        __syncthreads();
#pragma unroll
        for (int kk = 0; kk < 16; kk++) {
            const float4 a = *(const float4*)&Xs[kk][ty * 4];
            const float4 bb = *(const float4*)&Ys[kk][tx * 4];
            acc[0][0] += a.x * bb.x; acc[0][1] += a.x * bb.y; acc[0][2] += a.x * bb.z; acc[0][3] += a.x * bb.w;
            acc[1][0] += a.y * bb.x; acc[1][1] += a.y * bb.y; acc[1][2] += a.y * bb.z; acc[1][3] += a.y * bb.w;
            acc[2][0] += a.z * bb.x; acc[2][1] += a.z * bb.y; acc[2][2] += a.z * bb.z; acc[2][3] += a.z * bb.w;
            acc[3][0] += a.w * bb.x; acc[3][1] += a.w * bb.y; acc[3][2] += a.w * bb.z; acc[3][3] += a.w * bb.w;
        }
        __syncthreads();
    }

#pragma unroll
    for (int r = 0; r < 4; r++) {
        float4 o;
        float* op = &o.x;
#pragma unroll
        for (int c = 0; c < 4; c++) {
            const float x = acc[r][c];
            const float l = log1pf(expf(-fabsf(x)));
            op[c] = which ? (fminf(x, 0.0f) - l)     // log_sigmoid
                          : (fmaxf(x, 0.0f) + l);   // softplus
        }
        *(float4*)&C[(size_t)(row0 + ty * 4 + r) * M + col0 + tx * 4] = o;
    }
}

// ---------------------------------------------------------------------------
// Row-major theta,A -> compact-diag interleaved float2 {theta, A}, scaled by
// log2(e) so the DP kernel can use native exp2/log2 (p-ratios are invariant).
// ---------------------------------------------------------------------------
__global__ __launch_bounds__(256)
void reorder_in_kernel(const float* __restrict__ theta, const float* __restrict__ A,
                       float2* __restrict__ TAD)
{
    __shared__ float T[64][67];
    __shared__ float Ag[64][67];
    const int b = blockIdx.z;
    const float* ts = theta + (size_t)b * NM;
    const float* as = A + (size_t)b * NM;
    float2* dst = TAD + (size_t)b * NM;
    const int r0 = blockIdx.y * 64, c0 = blockIdx.x * 64;
    const int t = threadIdx.x, lane = t & 63, wv = t >> 6;

#pragma unroll
    for (int e = 0; e < 16; e++) {
        const int r = wv * 16 + e;
        T[r][lane]  = ts[(size_t)(r0 + r) * M + c0 + lane];
        Ag[r][lane] = as[(size_t)(r0 + r) * M + c0 + lane];
    }
    __syncthreads();
    for (int dd = wv; dd < 127; dd += 4) {
        const int kd = r0 + c0 + dd;
        const int rlo = max(0, dd - 63);
        const int L = min(63, dd) - rlo + 1;
        if (lane < L) {
            const int rloc = rlo + lane;
            const int gr = r0 + rloc;
            dst[diag_off(kd) + gr - max(0, kd - 511)] =
                make_float2(T[rloc][dd - rloc] * LOG2E, Ag[rloc][dd - rloc] * LOG2E);
        }
    }
}

// ---------------------------------------------------------------------------
// Compact-diag E -> row-major aln.
// ---------------------------------------------------------------------------
__global__ __launch_bounds__(256)
void reorder_out_kernel(const float* __restrict__ ED, float* __restrict__ aln)
{
    __shared__ float T[64][67];
    const int b = blockIdx.z;
    const float* src = ED + (size_t)b * NM;
    float* dst = aln + (size_t)b * NM;
    const int r0 = blockIdx.y * 64, c0 = blockIdx.x * 64;
    const int t = threadIdx.x, lane = t & 63, wv = t >> 6;

    for (int dd = wv; dd < 127; dd += 4) {
        const int kd = r0 + c0 + dd;
        const int rlo = max(0, dd - 63);
        const int L = min(63, dd) - rlo + 1;
        if (lane < L) {
            const int rloc = rlo + lane;
            const int gr = r0 + rloc;
            T[rloc][dd - rloc] = src[diag_off(kd) + gr - max(0, kd - 511)];
        }
    }
    __syncthreads();
#pragma unroll
    for (int e = 0; e < 16; e++) {
        const int r = wv * 16 + e;
        dst[(size_t)(r0 + r) * M + c0 + lane] = T[r][lane];
    }
}

// ---------------------------------------------------------------------------
// Fences. Chunk top: if the previous chunk issued exactly 16 stores (interior
// path), vmcnt(16) drains ONLY the 16 older loads and leaves stores in flight.
// CHUNK_BARRIER: LDS drain + raw s_barrier; loads/stores stay in flight.
// ---------------------------------------------------------------------------
#define VMCNT_TOP_PF                                        \
    if (pf) { asm volatile("s_waitcnt vmcnt(16)"); }        \
    else    { asm volatile("s_waitcnt vmcnt(0)");  }        \
    __builtin_amdgcn_sched_barrier(0);

#define CHUNK_BARRIER                          \
    __builtin_amdgcn_sched_barrier(0);         \
    asm volatile("s_waitcnt lgkmcnt(0)");      \
    __builtin_amdgcn_s_barrier();              \
    __builtin_amdgcn_sched_barrier(0);

#define DECL16(P)  f32x2 P##0, P##1, P##2, P##3, P##4, P##5, P##6, P##7, \
                         P##8, P##9, P##10, P##11, P##12, P##13, P##14, P##15;
#define DECL16F(P) float P##0, P##1, P##2, P##3, P##4, P##5, P##6, P##7, \
                         P##8, P##9, P##10, P##11, P##12, P##13, P##14, P##15;

// ---------------------------------------------------------------------------
// Forward soft-NW. Rolled loop, streaming diag addressing, asm prefetch,
// batched global stores, and BATCHED b128 RING I/O:
//   ring slot(kd) = kd & 63 (kb % 16 == 0 -> 16-aligned windows).
//   Read: 4x ds_read_b128 (wave-uniform broadcast) of V_{w-1} at [kb, kb+15];
//   step 0 uses carry gcar = previous window's top (kd = kb-1).
//   Write: lane 63 flushes its 16 vprev values as 4x ds_write_b128 at chunk end.
// ---------------------------------------------------------------------------
#define FLOAD1(dst) {                                          \
    asm volatile("global_load_dwordx2 %0, %1, %2"              \
                 : "=v"(dst) : "v"(off8l), "s"(tab));          \
    const int d_ = (kdl <= 510) ? max(kdl + 1, 0)              \
                                : max(1022 - kdl, 0);          \
    off8l += d_ * 8; kdl++;                                    \
}
#define F_ISSUE(P) {                                           \
    FLOAD1(P##0)  FLOAD1(P##1)  FLOAD1(P##2)  FLOAD1(P##3)     \
    FLOAD1(P##4)  FLOAD1(P##5)  FLOAD1(P##6)  FLOAD1(P##7)     \
    FLOAD1(P##8)  FLOAD1(P##9)  FLOAD1(P##10) FLOAD1(P##11)    \
    FLOAD1(P##12) FLOAD1(P##13) FLOAD1(P##14) FLOAD1(P##15)    \
}

#define F_CORE(kd_, TA, sh1v, dgv, O) {                        \
    const float th = (TA).x, a = (TA).y;                       \
    const float x0 = a + sh1v;                                 \
    const float x2 = a + vprev;                                \
    const float mx = fmaxf(fmaxf(x0, dgv), x2);                \
    const float e0 = EXP2F(x0 - mx);                           \
    const float e1 = EXP2F(dgv - mx);                          \
    const float e2 = EXP2F(x2 - mx);                           \
    const float sum = e0 + e1 + e2;                            \
    const float inv = __builtin_amdgcn_rcpf(sum);              \
    (O).x = e0 * inv; (O).y = e2 * inv;                        \
    vprev = th + mx + LOG2F(sum);                              \
}

// interior: every lane valid, jj>=1 guaranteed -> no selects, no exec juggling
#define F_STEP_I(s, TA, O, RG) {                               \
    float sh1 = dpp_shr1(vprev);                               \
    if (lane == 0) sh1 = RG;                                   \
    const float dgv = sh1_d;                                   \
    sh1_d = sh1;                                               \
    F_CORE(kb + (s), TA, sh1, dgv, O)                          \
    wv##s = vprev;                                             \
}

#define F_STEP_G(s, TA, O, RG) {                               \
    const int kd = kb + (s);                                   \
    const int jj = kd - tid;                                   \
    float sh1 = dpp_shr1(vprev);                               \
    if (lane == 0) sh1 = RG;                                   \
    const float dgv = (jj == 0) ? ((tid == 0) ? 0.0f : NEG) : sh1_d; \
    sh1_d = sh1;                                               \
    if (jj >= 0 && jj < M) { F_CORE(kd, TA, sh1, dgv, O) }     \
    wv##s = vprev;                                             \
}

#define F_STEPS(SFX, CUR)                                                      \
    F_STEP_##SFX(0,  CUR##0,  o0,  rgP) F_STEP_##SFX(1,  CUR##1,  o1,  g0)     \
    F_STEP_##SFX(2,  CUR##2,  o2,  g1)  F_STEP_##SFX(3,  CUR##3,  o3,  g2)     \
    F_STEP_##SFX(4,  CUR##4,  o4,  g3)  F_STEP_##SFX(5,  CUR##5,  o5,  g4)     \
    F_STEP_##SFX(6,  CUR##6,  o6,  g5)  F_STEP_##SFX(7,  CUR##7,  o7,  g6)     \
    F_STEP_##SFX(8,  CUR##8,  o8,  g7)  F_STEP_##SFX(9,  CUR##9,  o9,  g8)     \
    F_STEP_##SFX(10, CUR##10, o10, g9)  F_STEP_##SFX(11, CUR##11, o11, g10)    \
    F_STEP_##SFX(12, CUR##12, o12, g11) F_STEP_##SFX(13, CUR##13, o13, g12)    \
    F_STEP_##SFX(14, CUR##14, o14, g13) F_STEP_##SFX(15, CUR##15, o15, g14)

#define F_ADV_S { const int d_ = (kds <= 510) ? (kds + 1) : (1022 - kds);    \
                  off8s += d_ * 8; kds++; }
#define FST_I(O) {                                                           \
    asm volatile("global_store_dwordx2 %0, %1, %2"                           \
                 :: "v"(off8s), "v"(O), "s"(pb) : "memory");                 \
    F_ADV_S }
#define FST_G(s, O) {                                                        \
    const int jj = kb + (s) - tid;                                           \
    if (jj >= 0 && jj < M) {                                                 \
        asm volatile("global_store_dwordx2 %0, %1, %2"                       \
                     :: "v"(off8s), "v"(O), "s"(pb) : "memory"); }           \
    F_ADV_S }
#define F_STORES_I {                                                         \
    FST_I(o0)  FST_I(o1)  FST_I(o2)  FST_I(o3)                               \
    FST_I(o4)  FST_I(o5)  FST_I(o6)  FST_I(o7)                               \
    FST_I(o8)  FST_I(o9)  FST_I(o10) FST_I(o11)                              \
    FST_I(o12) FST_I(o13) FST_I(o14) FST_I(o15) }
#define F_STORES_G {                                                         \
    FST_G(0,o0)   FST_G(1,o1)   FST_G(2,o2)   FST_G(3,o3)                    \
    FST_G(4,o4)   FST_G(5,o5)   FST_G(6,o6)   FST_G(7,o7)                    \
    FST_G(8,o8)   FST_G(9,o9)   FST_G(10,o10) FST_G(11,o11)                  \
    FST_G(12,o12) FST_G(13,o13) FST_G(14,o14) FST_G(15,o15) }

#define F_CHUNK(c_, CUR, NXT) {                                \
    const int c = (c_);                                        \
    VMCNT_TOP_PF             /* CUR loads now valid */         \
    F_ISSUE(NXT)             /* next-chunk loads in flight */  \
    const int kb = 16 * c - w16;                               \
    const int kr = kb - 64 * w;                                \
    const bool act = (c >= ca && c <= cb);                     \
    const bool interior = act && (kr >= 64) && (kr <= 496);    \
    const float rgP = gcar;                                    \
    if (w > 0 && c >= ca - 1 && c <= cb) {                     \
        const float4* rp = (const float4*)&ring[w - 1][kb & 63]; \
        const float4 A0 = rp[0], A1 = rp[1];                   \
        const float4 A2 = rp[2], A3 = rp[3];                   \
        g0  = A0.x; g1  = A0.y; g2  = A0.z; g3  = A0.w;        \
        g4  = A1.x; g5  = A1.y; g6  = A1.z; g7  = A1.w;        \
        g8  = A2.x; g9  = A2.y; g10 = A2.z; g11 = A2.w;        \
        g12 = A3.x; g13 = A3.y; g14 = A3.z; g15 = A3.w;        \
        gcar = g15;                                            \
    }                                                          \
    if (act) {                                                 \
        DECL16F(wv)                                            \
        DECL16(o)                                              \
        if (interior) {                                        \
            F_STEPS(I, CUR)                                    \
            F_STORES_I                                         \
        } else {                                               \
            F_STEPS(G, CUR)                                    \
            F_STORES_G                                         \
        }                                                      \
        if (lane == 63) {                                      \
            float4* wp = (float4*)&ring[w][kb & 63];           \
            wp[0] = make_float4(wv0,  wv1,  wv2,  wv3);        \
            wp[1] = make_float4(wv4,  wv5,  wv6,  wv7);        \
            wp[2] = make_float4(wv8,  wv9,  wv10, wv11);       \
            wp[3] = make_float4(wv12, wv13, wv14, wv15);       \
        }                                                      \
    }                                                          \
    pf = interior;                                             \
    CHUNK_BARRIER                                              \
}

__global__ __launch_bounds__(512, 1)
void nw_forward_kernel(const float2* __restrict__ TAD, float2* __restrict__ pD)
{
    __shared__ __align__(16) float ring[8][64];
    const int b = blockIdx.x;
    const int tid = threadIdx.x;
    const int w = __builtin_amdgcn_readfirstlane(tid >> 6);
    const int lane = tid & 63;
    const int w16 = 16 * w;
    const float2* tab = TAD + (size_t)b * NM;
    float2* pb = pD + (size_t)b * NM;

    for (int x = tid; x < 8 * 64; x += 512) ((float*)ring)[x] = NEG;
    __syncthreads();

    const int ca = 5 * w, cb = 5 * w + 35;

    // streaming address state (byte offsets; SGPR-base loads/stores)
    int kdl = -w16;
    int off8l = tid * 8;                              // extended fi(kd<=0) = tid
    int kds = 64 * w;
    int off8s = (((kds * (kds + 1)) >> 1) + tid) * 8; // fi(64w)

    DECL16(fa) DECL16(fb)
    F_ISSUE(fa)

    // persistent ring window + carry (w==0 never reads -> stays NEG = boundary)
    float g0 = NEG, g1 = NEG, g2 = NEG, g3 = NEG, g4 = NEG, g5 = NEG,
          g6 = NEG, g7 = NEG, g8 = NEG, g9 = NEG, g10 = NEG, g11 = NEG,
          g12 = NEG, g13 = NEG, g14 = NEG, g15 = NEG, gcar = NEG;

    float vprev = NEG, sh1_d = NEG;
    bool pf = false;

#pragma unroll 1
    for (int c2 = 0; c2 < NCHUNK; c2 += 2) {
        F_CHUNK(c2 + 0, fa, fb)
        F_CHUNK(c2 + 1, fb, fa)
    }
}

// ---------------------------------------------------------------------------
// Backward adjoint, mirrored skew (wave 7 leads), K0 = 1134. Batched b128
// ring I/O: slot(kd) = (kd+1) & 63 (kb % 16 == 14 -> aligned windows).
// Read: 8x ds_read_b128 of qu/qd_{w+1} at values [kb-15, kb]; step 0/1 use
// carries cu/cA/cB from the previous window ([kb+1, kb+16] lowest elements).
// Write: lane 0 flushes 16 qu + 16 qd as 8x ds_write_b128 (reverse order).
// ---------------------------------------------------------------------------
#define BLOAD1(dst) {                                          \
    asm volatile("global_load_dwordx2 %0, %1, %2"              \
                 : "=v"(dst) : "v"(off8l), "s"(pbp));          \
    const int d_ = (kdl <= 511) ? (-max(kdl, 0))               \
                                : min(kdl - 1023, 0);          \
    off8l += d_ * 8; kdl--;                                    \
}
#define B_ISSUE(P) {                                           \
    BLOAD1(P##0)  BLOAD1(P##1)  BLOAD1(P##2)  BLOAD1(P##3)     \
    BLOAD1(P##4)  BLOAD1(P##5)  BLOAD1(P##6)  BLOAD1(P##7)     \
    BLOAD1(P##8)  BLOAD1(P##9)  BLOAD1(P##10) BLOAD1(P##11)    \
    BLOAD1(P##12) BLOAD1(P##13) BLOAD1(P##14) BLOAD1(P##15)    \
}

#define B_CORE(kd_, PP, suv, sdv, EV, TERMFIX) {               \
    float e = suv + sdv + ql1;                                 \
    TERMFIX                                                    \
    const float pu = (PP).x, pl = (PP).y;                      \
    const float pd = 1.0f - pu - pl;                           \
    const float qu = pu * e, qd = pd * e, ql = pl * e;         \
    EV = e;                                                    \
    qd2 = qd1; qd1 = qd; qu1 = qu; ql1 = ql;                   \
}

#define B_STEP_I(s, PP, EV, RU, RD) {                          \
    float su = dpp_shl1(qu1);                                  \
    float sd = dpp_shl1(qd2);                                  \
    if (lane == 63) { su = RU; sd = RD; }                      \
    B_CORE(kb - (s), PP, su, sd, EV, )                         \
    wu##s = qu1; wd##s = qd1;                                  \
}

#define B_STEP_G(s, PP, EV, RU, RD) {                          \
    const int kd = kb - (s);                                   \
    const int jj = kd - tid;                                   \
    float su = dpp_shl1(qu1);                                  \
    float sd = dpp_shl1(qd2);                                  \
    if (lane == 63) { su = RU; sd = RD; }                      \
    if (jj >= 0 && jj < M) {                                   \
        B_CORE(kd, PP, su, sd, EV,                             \
               if (tid == N - 1 && jj == M - 1) e = 1.0f;)     \
    }                                                          \
    wu##s = qu1; wd##s = qd1;                                  \
}

#define B_STEPS(SFX, CUR)                                        \
    B_STEP_##SFX(0,  CUR##0,  ev0,  cuP,  cAP)                   \
    B_STEP_##SFX(1,  CUR##1,  ev1,  gu15, cBP)                   \
    B_STEP_##SFX(2,  CUR##2,  ev2,  gu14, gd15)                  \
    B_STEP_##SFX(3,  CUR##3,  ev3,  gu13, gd14)                  \
    B_STEP_##SFX(4,  CUR##4,  ev4,  gu12, gd13)                  \
    B_STEP_##SFX(5,  CUR##5,  ev5,  gu11, gd12)                  \
    B_STEP_##SFX(6,  CUR##6,  ev6,  gu10, gd11)                  \
    B_STEP_##SFX(7,  CUR##7,  ev7,  gu9,  gd10)                  \
    B_STEP_##SFX(8,  CUR##8,  ev8,  gu8,  gd9)                   \
    B_STEP_##SFX(9,  CUR##9,  ev9,  gu7,  gd8)                   \
    B_STEP_##SFX(10, CUR##10, ev10, gu6,  gd7)                   \
    B_STEP_##SFX(11, CUR##11, ev11, gu5,  gd6)                   \
    B_STEP_##SFX(12, CUR##12, ev12, gu4,  gd5)                   \
    B_STEP_##SFX(13, CUR##13, ev13, gu3,  gd4)                   \
    B_STEP_##SFX(14, CUR##14, ev14, gu2,  gd3)                   \
    B_STEP_##SFX(15, CUR##15, ev15, gu1,  gd2)

#define B_ADV_S { const int d_ = (kds <= 511) ? (-max(kds, 0))               \
                                              : min(kds - 1023, 0);          \
                  off4s += d_ * 4; kds--; }
#define BST_I(EV) {                                                          \
    asm volatile("global_store_dword %0, %1, %2"                             \
                 :: "v"(off4s), "v"(EV), "s"(ebp) : "memory");               \
    B_ADV_S }
#define BST_G(s, EV) {                                                       \
    const int jj = kb - (s) - tid;                                           \
    if (jj >= 0 && jj < M) {                                                 \
        asm volatile("global_store_dword %0, %1, %2"                         \
                     :: "v"(off4s), "v"(EV), "s"(ebp) : "memory"); }         \
    B_ADV_S }
#define B_STORES_I {                                                         \
    BST_I(ev0)  BST_I(ev1)  BST_I(ev2)  BST_I(ev3)                           \
    BST_I(ev4)  BST_I(ev5)  BST_I(ev6)  BST_I(ev7)                           \
    BST_I(ev8)  BST_I(ev9)  BST_I(ev10) BST_I(ev11)                          \
    BST_I(ev12) BST_I(ev13) BST_I(ev14) BST_I(ev15) }
#define B_STORES_G {                                                         \
    BST_G(0,ev0)   BST_G(1,ev1)   BST_G(2,ev2)   BST_G(3,ev3)                \
    BST_G(4,ev4)   BST_G(5,ev5)   BST_G(6,ev6)   BST_G(7,ev7)                \
    BST_G(8,ev8)   BST_G(9,ev9)   BST_G(10,ev10) BST_G(11,ev11)              \
    BST_G(12,ev12) BST_G(13,ev13) BST_G(14,ev14) BST_G(15,ev15) }

#define B_CHUNK(c_, CUR, NXT) {                                \
    const int c = (c_);                                        \
    VMCNT_TOP_PF                                               \
    B_ISSUE(NXT)                                               \
    const int kb = 1134 - 16 * c - w16;                        \
    const int krb = kb - 64 * w;                               \
    const bool act = (c >= ca && c <= cb);                     \
    const bool interior = act && (krb >= 78) && (krb <= 511);  \
    const float cuP = cu, cAP = cA, cBP = cB;                  \
    if (w < 7 && c >= ca - 1 && c <= cb) {                     \
        const int rb = (kb - 14) & 63;                         \
        const float4* up = (const float4*)&ring_u[w + 1][rb];  \
        const float4 U0 = up[0], U1 = up[1];                   \
        const float4 U2 = up[2], U3 = up[3];                   \
        gu0  = U0.x; gu1  = U0.y; gu2  = U0.z; gu3  = U0.w;    \
        gu4  = U1.x; gu5  = U1.y; gu6  = U1.z; gu7  = U1.w;    \
        gu8  = U2.x; gu9  = U2.y; gu10 = U2.z; gu11 = U2.w;    \
        gu12 = U3.x; gu13 = U3.y; gu14 = U3.z; gu15 = U3.w;    \
        const float4* dp = (const float4*)&ring_d[w + 1][rb];  \
        const float4 D0 = dp[0], D1 = dp[1];                   \
        const float4 D2 = dp[2], D3 = dp[3];                   \
        gd0  = D0.x; gd1  = D0.y; gd2  = D0.z; gd3  = D0.w;    \
        gd4  = D1.x; gd5  = D1.y; gd6  = D1.z; gd7  = D1.w;    \
        gd8  = D2.x; gd9  = D2.y; gd10 = D2.z; gd11 = D2.w;    \
        gd12 = D3.x; gd13 = D3.y; gd14 = D3.z; gd15 = D3.w;    \
        cu = gu0; cA = gd1; cB = gd0;                          \
    }                                                          \
    if (act) {                                                 \
        DECL16F(wu) DECL16F(wd) DECL16F(ev)                    \
        if (interior) {                                        \
            B_STEPS(I, CUR)                                    \
            B_STORES_I                                         \
        } else {                                               \
            B_STEPS(G, CUR)                                    \
            B_STORES_G                                         \
        }                                                      \
        if (lane == 0) {                                       \
            const int rb2 = (kb - 14) & 63;                    \
            float4* au = (float4*)&ring_u[w][rb2];             \
            au[0] = make_float4(wu15, wu14, wu13, wu12);       \
            au[1] = make_float4(wu11, wu10, wu9,  wu8);        \
            au[2] = make_float4(wu7,  wu6,  wu5,  wu4);        \
            au[3] = make_float4(wu3,  wu2,  wu1,  wu0);        \
            float4* ad = (float4*)&ring_d[w][rb2];             \
            ad[0] = make_float4(wd15, wd14, wd13, wd12);       \
            ad[1] = make_float4(wd11, wd10, wd9,  wd8);        \
            ad[2] = make_float4(wd7,  wd6,  wd5,  wd4);        \
            ad[3] = make_float4(wd3,  wd2,  wd1,  wd0);        \
        }                                                      \
    }                                                          \
    pf = interior;                                             \
    CHUNK_BARRIER                                              \
}

__global__ __launch_bounds__(512, 1)
void nw_backward_kernel(const float2* __restrict__ pD, float* __restrict__ ED)
{
    __shared__ __align__(16) float ring_u[8][64];
    __shared__ __align__(16) float ring_d[8][64];
    const int b = blockIdx.x;
    const int tid = threadIdx.x;
    const int w = __builtin_amdgcn_readfirstlane(tid >> 6);
    const int lane = tid & 63;
    const int w16 = 16 * w;
    const float2* pbp = pD + (size_t)b * NM;
    float* ebp = ED + (size_t)b * NM;

    for (int x = tid; x < 8 * 64; x += 512) {
        ((float*)ring_u)[x] = 0.0f;
        ((float*)ring_d)[x] = 0.0f;
    }
    __syncthreads();

    const int ca = 35 - 5 * w, cb = 70 - 5 * w;

    // streaming address state (descending)
    int kdl = 1134 - w16;
    int off8l = ((int)NM - 512 + tid) * 8;           // fi(1022)
    int kds = 574 + 64 * w;                          // first active store kd
    const int am_ = 1023 - kds, bm_ = 1024 - kds;
    int off4s = ((int)NM - ((am_ * bm_) >> 1) + tid - (kds - 511)) * 4;

    DECL16(ba) DECL16(bb)
    B_ISSUE(ba)

    // persistent ring windows + carries (w==7 never reads -> stays 0 = boundary)
    float gu0 = 0.f, gu1 = 0.f, gu2 = 0.f, gu3 = 0.f, gu4 = 0.f, gu5 = 0.f,
          gu6 = 0.f, gu7 = 0.f, gu8 = 0.f, gu9 = 0.f, gu10 = 0.f, gu11 = 0.f,
          gu12 = 0.f, gu13 = 0.f, gu14 = 0.f, gu15 = 0.f;
    float gd0 = 0.f, gd1 = 0.f, gd2 = 0.f, gd3 = 0.f, gd4 = 0.f, gd5 = 0.f,
          gd6 = 0.f, gd7 = 0.f, gd8 = 0.f, gd9 = 0.f, gd10 = 0.f, gd11 = 0.f,
          gd12 = 0.f, gd13 = 0.f, gd14 = 0.f, gd15 = 0.f;
    float cu = 0.f, cA = 0.f, cB = 0.f;

    float qu1 = 0.0f, qd1 = 0.0f, qd2 = 0.0f, ql1 = 0.0f;
    bool pf = false;

#pragma unroll 1
    for (int c2 = 0; c2 < NCHUNK; c2 += 2) {
        B_CHUNK(c2 + 0, ba, bb)
        B_CHUNK(c2 + 1, bb, ba)
    }
}

// ---------------------------------------------------------------------------
extern "C" void kernel_launch(void* const* d_in, const int* in_sizes, int n_in,
                              void* d_out, int out_size, void* d_ws, size_t ws_size,
                              hipStream_t stream) {
    const float* zx = (const float*)d_in[0];
    const float* zy = (const float*)d_in[1];
    const float* gx = (const float*)d_in[2];
    const float* gy = (const float*)d_in[3];

    float* aln   = (float*)d_out;               // output 0: [B,N,M]
    float* theta = aln + B * NM;                // output 1
    float* Amat  = theta + B * NM;              // output 2

    float2* TAD = (float2*)d_ws;                // {theta,A}*log2e diag-interleaved
    float2* pD  = TAD + B * NM;                 // {p_up,p_lf} diag-interleaved
    float*  ED  = (float*)d_ws;                 // overlays TAD (dead after forward)

    gemm_act_kernel<<<dim3(8, 8, B * 2), dim3(16, 16), 0, stream>>>(zx, zy, gx, gy, theta, Amat);
    reorder_in_kernel<<<dim3(8, 8, B), 256, 0, stream>>>(theta, Amat, TAD);
    nw_forward_kernel<<<B, 512, 0, stream>>>(TAD, pD);
    nw_backward_kernel<<<B, 512, 0, stream>>>(pD, ED);
    reorder_out_kernel<<<dim3(8, 8, B), 256, 0, stream>>>(ED, aln);
}